// Round 22
// baseline (149.887 us; speedup 1.0000x reference)
//
#include <hip/hip_runtime.h>
#include <hip/hip_bf16.h>

#define B_   4
#define T_   2048
#define E_   1024
#define NH_  16
#define HS_  64
#define F_   (3 * E_)   // 3072
#define M_   (B_ * T_)  // 8192

typedef short bf16x8 __attribute__((ext_vector_type(8)));
typedef float f32x4  __attribute__((ext_vector_type(4)));
typedef float f32x16 __attribute__((ext_vector_type(16)));

__device__ __forceinline__ short f2bf(float f) {
    __hip_bfloat16 h = __float2bfloat16(f);
    return *reinterpret_cast<short*>(&h);
}

__device__ __forceinline__ bf16x8 pack2(float4 a, float4 b) {
    bf16x8 r;
    r[0] = f2bf(a.x); r[1] = f2bf(a.y); r[2] = f2bf(a.z); r[3] = f2bf(a.w);
    r[4] = f2bf(b.x); r[5] = f2bf(b.y); r[6] = f2bf(b.z); r[7] = f2bf(b.w);
    return r;
}

// HW packed f32->bf16 (RNE)
__device__ __forceinline__ unsigned cvtpk(float a, float b) {
    unsigned r;
    asm("v_cvt_pk_bf16_f32 %0, %1, %2" : "=v"(r) : "v"(a), "v"(b));
    return r;
}

// raw HW 2^x (single instruction)
__device__ __forceinline__ float hexp2(float x) {
    float r;
    asm("v_exp_f32 %0, %1" : "=v"(r) : "v"(x));
    return r;
}

__device__ __forceinline__ void gload16(const void* g, void* l) {
    __builtin_amdgcn_global_load_lds(
        (const __attribute__((address_space(1))) unsigned int*)g,
        (__attribute__((address_space(3))) unsigned int*)l, 16, 0, 0);
}

// ---------------- fp32 -> bf16 pre-pass for X and W ----------------
__global__ __launch_bounds__(256) void cvt_bf16(const float* __restrict__ X,
                                                const float* __restrict__ W,
                                                short* __restrict__ Xb,
                                                short* __restrict__ Wb) {
    const long nX = (long)M_ * E_;   // 8388608
    long i = ((long)blockIdx.x * 256 + threadIdx.x) * 8;
    const float* src;
    short* dst;
    long off;
    if (i < nX) { src = X; dst = Xb; off = i; }
    else        { src = W; dst = Wb; off = i - nX; }
    float4 a = *(const float4*)(src + off);
    float4 b = *(const float4*)(src + off + 4);
    *(bf16x8*)(dst + off) = pack2(a, b);
}

// ---------------- QKV GEMM v4b: R19 structure, 3 blocks/CU (768 = exactly one round) ----------------
#define NT 32  // K / 32

__global__ __launch_bounds__(256, 3) void qkv_gemm_mfma(const short* __restrict__ Xb,
                                                        const short* __restrict__ Wb,
                                                        const float* __restrict__ bias,
                                                        __hip_bfloat16* __restrict__ Qb,
                                                        __hip_bfloat16* __restrict__ Kb,
                                                        __hip_bfloat16* __restrict__ Vf) {
    __shared__ __align__(16) short lds[2 * 12288];   // 48 KB

    const int tid = threadIdx.x;
    const int w = tid >> 6, l = tid & 63;
    const int lg = l >> 4, lr = l & 15;
    const int wm = w >> 1, wn = w & 1;   // wave tile 128 rows x 64 cols

    const int bid = blockIdx.x;
    const int sw = (bid & 7) * 96 + (bid >> 3);
    const int bm = sw / 24, bn = sw % 24;

    const int Rs  = tid >> 3;
    const int cls = (tid & 7) ^ (Rs & 7);
    const int gr1 = 2 * Rs + (cls >> 2);
    const int k0s = (cls & 3) * 8;
    const short* gA = Xb + (long)(bm * 256 + gr1) * E_ + k0s;
    const short* gB = Wb + (long)(bn * 128 + gr1) * E_ + k0s;
    const int dOff = w * 512;

    const f32x4 zero = {0.f, 0.f, 0.f, 0.f};
    f32x4 acc[8][4];
#pragma unroll
    for (int i = 0; i < 8; ++i)
#pragma unroll
        for (int j = 0; j < 4; ++j) acc[i][j] = zero;

#define STAGE(t, p)                                                   \
    {                                                                 \
        const int ko = (t) * 32;                                      \
        short* lb = &lds[(p) * 12288];                                \
        gload16(gA + ko,                  &lb[dOff]);                 \
        gload16(gA + ko + (long) 64 * E_, &lb[2048 + dOff]);          \
        gload16(gA + ko + (long)128 * E_, &lb[4096 + dOff]);          \
        gload16(gA + ko + (long)192 * E_, &lb[4096 + 2048 + dOff]);   \
        gload16(gB + ko,                  &lb[8192 + dOff]);          \
        gload16(gB + ko + (long) 64 * E_, &lb[8192 + 2048 + dOff]);   \
    }

    STAGE(0, 0);

    for (int t = 0; t < NT; ++t) {
        const int p = t & 1;
        asm volatile("s_waitcnt vmcnt(0)" ::: "memory");
        __builtin_amdgcn_s_barrier();
        __builtin_amdgcn_sched_barrier(0);
        if (t + 1 < NT) STAGE(t + 1, p ^ 1);

        const short* lA = &lds[p * 12288 + wm * 4096];
        const short* lB = &lds[p * 12288 + 8192];
        const int c8 = (lr & 1) * 4 + lg;

        bf16x8 bf[4];
#pragma unroll
        for (int ng = 0; ng < 4; ++ng) {
            const int R = wn * 32 + ng * 8 + (lr >> 1);
            bf[ng] = *(const bf16x8*)&lB[R * 64 + (c8 ^ (R & 7)) * 8];
        }
        __builtin_amdgcn_s_setprio(1);
#pragma unroll
        for (int mg = 0; mg < 8; ++mg) {
            const int R = mg * 8 + (lr >> 1);
            bf16x8 af = *(const bf16x8*)&lA[R * 64 + (c8 ^ (R & 7)) * 8];
#pragma unroll
            for (int ng = 0; ng < 4; ++ng)
                acc[mg][ng] = __builtin_amdgcn_mfma_f32_16x16x32_bf16(af, bf[ng], acc[mg][ng], 0, 0, 0);
        }
        __builtin_amdgcn_s_setprio(0);
    }

    const int sec = bn >> 3;
    const float QSCALE = 0.125f * 1.44269504f;
#pragma unroll
    for (int mg = 0; mg < 8; ++mg)
#pragma unroll
        for (int ng = 0; ng < 4; ++ng) {
            const int row0 = bm * 256 + wm * 128 + mg * 16 + 4 * lg;
            const int col = bn * 128 + wn * 64 + ng * 16 + lr;
            const int cc = col & 1023;
            const int h = cc >> 6, d = cc & 63;
            const int b = row0 >> 11, t0 = row0 & 2047;
            const int bh = b * 16 + h;
            const float bia = bias[col];
            if (sec == 0) {
#pragma unroll
                for (int r = 0; r < 4; ++r)
                    Qb[((long)bh * T_ + t0 + r) * 64 + d] = __float2bfloat16((acc[mg][ng][r] + bia) * QSCALE);
            } else if (sec == 1) {
#pragma unroll
                for (int r = 0; r < 4; ++r)
                    Kb[((long)bh * T_ + t0 + r) * 64 + d] = __float2bfloat16(acc[mg][ng][r] + bia);
            } else {
                const int ktv = t0 >> 6, stv = (t0 >> 5) & 1, ksv = (t0 >> 4) & 1;
                const int hi8 = (t0 >> 3) & 1, j0 = t0 & 7;
                const int lanev = hi8 * 32 + (d & 31);
                const int dtv = d >> 5;
                const long off = (long)bh * 131072 +
                                 ((((((long)ktv * 2 + stv) * 2 + ksv) * 2 + dtv) * 64 + lanev) * 8 + j0);
                uint2 pk;
                pk.x = cvtpk(acc[mg][ng][0] + bia, acc[mg][ng][1] + bia);
                pk.y = cvtpk(acc[mg][ng][2] + bia, acc[mg][ng][3] + bia);
                *(uint2*)((short*)Vf + off) = pk;
            }
        }
#undef STAGE
}

// ---------------- Flash attention v10b: R21 structure, 4 blocks/CU (1024 = exactly one round) ----------------
__global__ __launch_bounds__(256, 4) void attn_mfma10(const __hip_bfloat16* __restrict__ Qb,
                                                      const __hip_bfloat16* __restrict__ Kb,
                                                      const __hip_bfloat16* __restrict__ Vf,
                                                      float* __restrict__ out) {
    const int g = blockIdx.x;                 // 0..1023
    const int xcd = g & 7, kidx = g >> 3;     // 8 bh per XCD
    const int bh = xcd * 8 + (kidx & 7);
    const int qt = 15 - (kidx >> 3);          // big tiles dispatch first
    const int b = bh >> 4, h = bh & 15;
    const int tid = threadIdx.x;
    const int wv = tid >> 6, ln = tid & 63;
    const int hi = ln >> 5, q5 = ln & 31;

    __shared__ __align__(16) short kbuf[2 * 8192];   // 2 x 16KB K tiles (128 keys each)

    const short* qbase = (const short*)Qb + (long)bh * T_ * 64;
    const short* kbase = (const short*)Kb + (long)bh * T_ * 64;
    const short* vfrag = (const short*)Vf + (long)bh * 131072;

    const int wq0 = qt * 128 + wv * 32;
    const int qg = wq0 + q5;

    bf16x8 qf[4];
#pragma unroll
    for (int w = 0; w < 4; ++w)
        qf[w] = *(const bf16x8*)&qbase[(long)qg * 64 + w * 16 + hi * 8];

    const int r0 = wv * 8 + (ln >> 3);
    const int cs = (ln & 7) ^ (r0 & 7);
    const short* pK0 = kbase + (long)r0 * 64 + cs * 8;

#define KSTAGE2(kt2, p)                                            \
    {                                                              \
        short* bb = &kbuf[(p) * 8192];                             \
        const long ko = (long)(kt2) * 8192;                        \
        gload16(pK0 + ko,           bb + wv * 512);                \
        gload16(pK0 + ko + 32 * 64, bb + 2048 + wv * 512);         \
        gload16(pK0 + ko + 64 * 64, bb + 4096 + wv * 512);         \
        gload16(pK0 + ko + 96 * 64, bb + 6144 + wv * 512);         \
    }

    const f32x16 zero16 = {0.f,0.f,0.f,0.f, 0.f,0.f,0.f,0.f, 0.f,0.f,0.f,0.f, 0.f,0.f,0.f,0.f};
    f32x16 o0 = zero16, o1 = zero16;
    float lsum = 0.f;

    const int nkt2 = qt + 1;   // 128-key tiles
    KSTAGE2(0, 0);

    for (int kt2 = 0; kt2 < nkt2; ++kt2) {
        const int p = kt2 & 1;
        asm volatile("s_waitcnt vmcnt(0)" ::: "memory");
        __builtin_amdgcn_s_barrier();
        __builtin_amdgcn_sched_barrier(0);
        if (kt2 + 1 < nkt2) KSTAGE2(kt2 + 1, p ^ 1);

#pragma unroll
        for (int half = 0; half < 2; ++half) {
            const int kt = kt2 * 2 + half;
            if (kt * 64 > wq0 + 31) continue;
            const short* K_lds = &kbuf[p * 8192 + half * 4096];
            const bool act1 = (kt * 64 + 32) <= (wq0 + 31);

            const short* vb = vfrag + (long)kt * 4096 + (long)ln * 8;
            bf16x8 vfr[8];
#pragma unroll
            for (int i = 0; i < 8; ++i) vfr[i] = *(const bf16x8*)(vb + i * 512);

            f32x16 sa = zero16, sb = zero16;
            __builtin_amdgcn_s_setprio(1);
#pragma unroll
            for (int w = 0; w < 4; ++w) {
                bf16x8 kf = *(const bf16x8*)&K_lds[q5 * 64 + ((w * 2 + hi) ^ (q5 & 7)) * 8];
                sa = __builtin_amdgcn_mfma_f32_32x32x16_bf16(kf, qf[w], sa, 0, 0, 0);
            }
            if (act1) {
#pragma unroll
                for (int w = 0; w < 4; ++w) {
                    int key = 32 + q5;
                    bf16x8 kf = *(const bf16x8*)&K_lds[key * 64 + ((w * 2 + hi) ^ (key & 7)) * 8];
                    sb = __builtin_amdgcn_mfma_f32_32x32x16_bf16(kf, qf[w], sb, 0, 0, 0);
                }
            }
            __builtin_amdgcn_s_setprio(0);

            if (kt * 64 + 31 > wq0) {
#pragma unroll
                for (int r = 0; r < 16; ++r) {
                    int key = kt * 64 + (r & 3) + 8 * (r >> 2) + 4 * hi;
                    sa[r] = (key <= qg) ? sa[r] : -1e30f;
                }
            }
            if (act1 && (kt * 64 + 63 > wq0)) {
#pragma unroll
                for (int r = 0; r < 16; ++r) {
                    int key = kt * 64 + 32 + (r & 3) + 8 * (r >> 2) + 4 * hi;
                    sb[r] = (key <= qg) ? sb[r] : -1e30f;
                }
            }

            float rs = 0.f;
#pragma unroll
            for (int r = 0; r < 16; ++r) { sa[r] = hexp2(sa[r]); rs += sa[r]; }
            if (act1) {
#pragma unroll
                for (int r = 0; r < 16; ++r) { sb[r] = hexp2(sb[r]); rs += sb[r]; }
            }
            lsum += rs;

            __builtin_amdgcn_s_setprio(1);
#pragma unroll
            for (int st = 0; st < 2; ++st) {
                if (st == 1 && !act1) break;
                const f32x16& s = (st == 0) ? sa : sb;
                unsigned pkv[8];
#pragma unroll
                for (int i = 0; i < 8; ++i) pkv[i] = cvtpk(s[2 * i], s[2 * i + 1]);
#pragma unroll
                for (int ks = 0; ks < 2; ++ks) {
                    // permlane32_swap(a,b): a' = [a.lo, b.lo], b' = [a.hi, b.hi]
                    unsigned a0 = pkv[4 * ks],     b0 = pkv[4 * ks + 2];
                    unsigned a1 = pkv[4 * ks + 1], b1 = pkv[4 * ks + 3];
                    asm("v_permlane32_swap_b32 %0, %1" : "+v"(a0), "+v"(b0));
                    asm("v_permlane32_swap_b32 %0, %1" : "+v"(a1), "+v"(b1));
                    union { unsigned u[4]; bf16x8 v; } fr;
                    fr.u[0] = a0;
                    fr.u[1] = a1;
                    fr.u[2] = b0;
                    fr.u[3] = b1;
                    o0 = __builtin_amdgcn_mfma_f32_32x32x16_bf16(vfr[(st * 2 + ks) * 2],     fr.v, o0, 0, 0, 0);
                    o1 = __builtin_amdgcn_mfma_f32_32x32x16_bf16(vfr[(st * 2 + ks) * 2 + 1], fr.v, o1, 0, 0, 0);
                }
            }
            __builtin_amdgcn_s_setprio(0);
        }
    }
#undef KSTAGE2

    lsum += __shfl_xor(lsum, 32, 64);
    const float inv = 1.f / lsum;
    float* orow = out + ((long)b * T_ + qg) * E_ + h * HS_;
#pragma unroll
    for (int rg = 0; rg < 4; ++rg) {
        float4 v0, v1;
        v0.x = o0[rg * 4 + 0] * inv; v0.y = o0[rg * 4 + 1] * inv;
        v0.z = o0[rg * 4 + 2] * inv; v0.w = o0[rg * 4 + 3] * inv;
        v1.x = o1[rg * 4 + 0] * inv; v1.y = o1[rg * 4 + 1] * inv;
        v1.z = o1[rg * 4 + 2] * inv; v1.w = o1[rg * 4 + 3] * inv;
        *(float4*)&orow[8 * rg + 4 * hi]      = v0;
        *(float4*)&orow[32 + 8 * rg + 4 * hi] = v1;
    }
}

extern "C" void kernel_launch(void* const* d_in, const int* in_sizes, int n_in,
                              void* d_out, int out_size, void* d_ws, size_t ws_size,
                              hipStream_t stream) {
    const float* x     = (const float*)d_in[0];   // [4,2048,1024]
    const float* W_qkv = (const float*)d_in[1];   // [3072,1024]
    const float* b_qkv = (const float*)d_in[2];   // [3072]
    float* out = (float*)d_out;                   // [4,2048,1024]

    const long per = (long)64 * T_ * 64;          // 8,388,608 elems per buffer
    __hip_bfloat16* Qb = (__hip_bfloat16*)d_ws;
    __hip_bfloat16* Kb = Qb + per;
    __hip_bfloat16* Vf = Kb + per;                // fragment-major V
    short* Xb = (short*)(Vf + per);
    short* Wb = Xb + (long)M_ * E_;

    const long ncvt = ((long)M_ * E_ + (long)F_ * E_) / 8;
    cvt_bf16<<<(int)(ncvt / 256), 256, 0, stream>>>(x, W_qkv, Xb, Wb);

    qkv_gemm_mfma<<<768, 256, 0, stream>>>(Xb, Wb, b_qkv, Qb, Kb, Vf);

    attn_mfma10<<<1024, 256, 0, stream>>>(Qb, Kb, Vf, out);
}

// Round 23
// 117.096 us; speedup vs baseline: 1.2800x; 1.2800x over previous
//
#include <hip/hip_runtime.h>
#include <hip/hip_bf16.h>

#define B_   4
#define T_   2048
#define E_   1024
#define NH_  16
#define HS_  64
#define F_   (3 * E_)   // 3072
#define M_   (B_ * T_)  // 8192

typedef short bf16x8 __attribute__((ext_vector_type(8)));
typedef float f32x4  __attribute__((ext_vector_type(4)));
typedef float f32x16 __attribute__((ext_vector_type(16)));

__device__ __forceinline__ short f2bf(float f) {
    __hip_bfloat16 h = __float2bfloat16(f);
    return *reinterpret_cast<short*>(&h);
}

__device__ __forceinline__ bf16x8 pack2(float4 a, float4 b) {
    bf16x8 r;
    r[0] = f2bf(a.x); r[1] = f2bf(a.y); r[2] = f2bf(a.z); r[3] = f2bf(a.w);
    r[4] = f2bf(b.x); r[5] = f2bf(b.y); r[6] = f2bf(b.z); r[7] = f2bf(b.w);
    return r;
}

// HW packed f32->bf16 (RNE)
__device__ __forceinline__ unsigned cvtpk(float a, float b) {
    unsigned r;
    asm("v_cvt_pk_bf16_f32 %0, %1, %2" : "=v"(r) : "v"(a), "v"(b));
    return r;
}

// raw HW 2^x (single instruction)
__device__ __forceinline__ float hexp2(float x) {
    float r;
    asm("v_exp_f32 %0, %1" : "=v"(r) : "v"(x));
    return r;
}

__device__ __forceinline__ void gload16(const void* g, void* l) {
    __builtin_amdgcn_global_load_lds(
        (const __attribute__((address_space(1))) unsigned int*)g,
        (__attribute__((address_space(3))) unsigned int*)l, 16, 0, 0);
}

// ---------------- fp32 -> bf16 pre-pass for X and W ----------------
__global__ __launch_bounds__(256) void cvt_bf16(const float* __restrict__ X,
                                                const float* __restrict__ W,
                                                short* __restrict__ Xb,
                                                short* __restrict__ Wb) {
    const long nX = (long)M_ * E_;   // 8388608
    long i = ((long)blockIdx.x * 256 + threadIdx.x) * 8;
    const float* src;
    short* dst;
    long off;
    if (i < nX) { src = X; dst = Xb; off = i; }
    else        { src = W; dst = Wb; off = i - nX; }
    float4 a = *(const float4*)(src + off);
    float4 b = *(const float4*)(src + off + 4);
    *(bf16x8*)(dst + off) = pack2(a, b);
}

// ---------------- QKV GEMM v4b (R22): 256x128 tile, wave 128x64, single-barrier dbuf, 3 blocks/CU ----------------
#define NT 32  // K / 32

__global__ __launch_bounds__(256, 3) void qkv_gemm_mfma(const short* __restrict__ Xb,
                                                        const short* __restrict__ Wb,
                                                        const float* __restrict__ bias,
                                                        __hip_bfloat16* __restrict__ Qb,
                                                        __hip_bfloat16* __restrict__ Kb,
                                                        __hip_bfloat16* __restrict__ Vf) {
    __shared__ __align__(16) short lds[2 * 12288];   // 48 KB

    const int tid = threadIdx.x;
    const int w = tid >> 6, l = tid & 63;
    const int lg = l >> 4, lr = l & 15;
    const int wm = w >> 1, wn = w & 1;   // wave tile 128 rows x 64 cols

    const int bid = blockIdx.x;
    const int sw = (bid & 7) * 96 + (bid >> 3);
    const int bm = sw / 24, bn = sw % 24;

    const int Rs  = tid >> 3;
    const int cls = (tid & 7) ^ (Rs & 7);
    const int gr1 = 2 * Rs + (cls >> 2);
    const int k0s = (cls & 3) * 8;
    const short* gA = Xb + (long)(bm * 256 + gr1) * E_ + k0s;
    const short* gB = Wb + (long)(bn * 128 + gr1) * E_ + k0s;
    const int dOff = w * 512;

    const f32x4 zero = {0.f, 0.f, 0.f, 0.f};
    f32x4 acc[8][4];
#pragma unroll
    for (int i = 0; i < 8; ++i)
#pragma unroll
        for (int j = 0; j < 4; ++j) acc[i][j] = zero;

#define STAGE(t, p)                                                   \
    {                                                                 \
        const int ko = (t) * 32;                                      \
        short* lb = &lds[(p) * 12288];                                \
        gload16(gA + ko,                  &lb[dOff]);                 \
        gload16(gA + ko + (long) 64 * E_, &lb[2048 + dOff]);          \
        gload16(gA + ko + (long)128 * E_, &lb[4096 + dOff]);          \
        gload16(gA + ko + (long)192 * E_, &lb[4096 + 2048 + dOff]);   \
        gload16(gB + ko,                  &lb[8192 + dOff]);          \
        gload16(gB + ko + (long) 64 * E_, &lb[8192 + 2048 + dOff]);   \
    }

    STAGE(0, 0);

    for (int t = 0; t < NT; ++t) {
        const int p = t & 1;
        asm volatile("s_waitcnt vmcnt(0)" ::: "memory");
        __builtin_amdgcn_s_barrier();
        __builtin_amdgcn_sched_barrier(0);
        if (t + 1 < NT) STAGE(t + 1, p ^ 1);

        const short* lA = &lds[p * 12288 + wm * 4096];
        const short* lB = &lds[p * 12288 + 8192];
        const int c8 = (lr & 1) * 4 + lg;

        bf16x8 bf[4];
#pragma unroll
        for (int ng = 0; ng < 4; ++ng) {
            const int R = wn * 32 + ng * 8 + (lr >> 1);
            bf[ng] = *(const bf16x8*)&lB[R * 64 + (c8 ^ (R & 7)) * 8];
        }
        __builtin_amdgcn_s_setprio(1);
#pragma unroll
        for (int mg = 0; mg < 8; ++mg) {
            const int R = mg * 8 + (lr >> 1);
            bf16x8 af = *(const bf16x8*)&lA[R * 64 + (c8 ^ (R & 7)) * 8];
#pragma unroll
            for (int ng = 0; ng < 4; ++ng)
                acc[mg][ng] = __builtin_amdgcn_mfma_f32_16x16x32_bf16(af, bf[ng], acc[mg][ng], 0, 0, 0);
        }
        __builtin_amdgcn_s_setprio(0);
    }

    const int sec = bn >> 3;
    const float QSCALE = 0.125f * 1.44269504f;
#pragma unroll
    for (int mg = 0; mg < 8; ++mg)
#pragma unroll
        for (int ng = 0; ng < 4; ++ng) {
            const int row0 = bm * 256 + wm * 128 + mg * 16 + 4 * lg;
            const int col = bn * 128 + wn * 64 + ng * 16 + lr;
            const int cc = col & 1023;
            const int h = cc >> 6, d = cc & 63;
            const int b = row0 >> 11, t0 = row0 & 2047;
            const int bh = b * 16 + h;
            const float bia = bias[col];
            if (sec == 0) {
#pragma unroll
                for (int r = 0; r < 4; ++r)
                    Qb[((long)bh * T_ + t0 + r) * 64 + d] = __float2bfloat16((acc[mg][ng][r] + bia) * QSCALE);
            } else if (sec == 1) {
#pragma unroll
                for (int r = 0; r < 4; ++r)
                    Kb[((long)bh * T_ + t0 + r) * 64 + d] = __float2bfloat16(acc[mg][ng][r] + bia);
            } else {
                const int ktv = t0 >> 6, stv = (t0 >> 5) & 1, ksv = (t0 >> 4) & 1;
                const int hi8 = (t0 >> 3) & 1, j0 = t0 & 7;
                const int lanev = hi8 * 32 + (d & 31);
                const int dtv = d >> 5;
                const long off = (long)bh * 131072 +
                                 ((((((long)ktv * 2 + stv) * 2 + ksv) * 2 + dtv) * 64 + lanev) * 8 + j0);
                uint2 pk;
                pk.x = cvtpk(acc[mg][ng][0] + bia, acc[mg][ng][1] + bia);
                pk.y = cvtpk(acc[mg][ng][2] + bia, acc[mg][ng][3] + bia);
                *(uint2*)((short*)Vf + off) = pk;
            }
        }
#undef STAGE
}

// ---------------- Flash attention v10 (R21 exact): (256,3), permlane32_swap P assembly ----------------
__global__ __launch_bounds__(256, 3) void attn_mfma10(const __hip_bfloat16* __restrict__ Qb,
                                                      const __hip_bfloat16* __restrict__ Kb,
                                                      const __hip_bfloat16* __restrict__ Vf,
                                                      float* __restrict__ out) {
    const int g = blockIdx.x;                 // 0..1023
    const int xcd = g & 7, kidx = g >> 3;     // 8 bh per XCD
    const int bh = xcd * 8 + (kidx & 7);
    const int qt = 15 - (kidx >> 3);          // big tiles dispatch first
    const int b = bh >> 4, h = bh & 15;
    const int tid = threadIdx.x;
    const int wv = tid >> 6, ln = tid & 63;
    const int hi = ln >> 5, q5 = ln & 31;

    __shared__ __align__(16) short kbuf[2 * 8192];   // 2 x 16KB K tiles (128 keys each)

    const short* qbase = (const short*)Qb + (long)bh * T_ * 64;
    const short* kbase = (const short*)Kb + (long)bh * T_ * 64;
    const short* vfrag = (const short*)Vf + (long)bh * 131072;

    const int wq0 = qt * 128 + wv * 32;
    const int qg = wq0 + q5;

    bf16x8 qf[4];
#pragma unroll
    for (int w = 0; w < 4; ++w)
        qf[w] = *(const bf16x8*)&qbase[(long)qg * 64 + w * 16 + hi * 8];

    const int r0 = wv * 8 + (ln >> 3);
    const int cs = (ln & 7) ^ (r0 & 7);
    const short* pK0 = kbase + (long)r0 * 64 + cs * 8;

#define KSTAGE2(kt2, p)                                            \
    {                                                              \
        short* bb = &kbuf[(p) * 8192];                             \
        const long ko = (long)(kt2) * 8192;                        \
        gload16(pK0 + ko,           bb + wv * 512);                \
        gload16(pK0 + ko + 32 * 64, bb + 2048 + wv * 512);         \
        gload16(pK0 + ko + 64 * 64, bb + 4096 + wv * 512);         \
        gload16(pK0 + ko + 96 * 64, bb + 6144 + wv * 512);         \
    }

    const f32x16 zero16 = {0.f,0.f,0.f,0.f, 0.f,0.f,0.f,0.f, 0.f,0.f,0.f,0.f, 0.f,0.f,0.f,0.f};
    f32x16 o0 = zero16, o1 = zero16;
    float lsum = 0.f;

    const int nkt2 = qt + 1;   // 128-key tiles
    KSTAGE2(0, 0);

    for (int kt2 = 0; kt2 < nkt2; ++kt2) {
        const int p = kt2 & 1;
        asm volatile("s_waitcnt vmcnt(0)" ::: "memory");
        __builtin_amdgcn_s_barrier();
        __builtin_amdgcn_sched_barrier(0);
        if (kt2 + 1 < nkt2) KSTAGE2(kt2 + 1, p ^ 1);

#pragma unroll
        for (int half = 0; half < 2; ++half) {
            const int kt = kt2 * 2 + half;
            if (kt * 64 > wq0 + 31) continue;
            const short* K_lds = &kbuf[p * 8192 + half * 4096];
            const bool act1 = (kt * 64 + 32) <= (wq0 + 31);

            const short* vb = vfrag + (long)kt * 4096 + (long)ln * 8;
            bf16x8 vfr[8];
#pragma unroll
            for (int i = 0; i < 8; ++i) vfr[i] = *(const bf16x8*)(vb + i * 512);

            f32x16 sa = zero16, sb = zero16;
            __builtin_amdgcn_s_setprio(1);
#pragma unroll
            for (int w = 0; w < 4; ++w) {
                bf16x8 kf = *(const bf16x8*)&K_lds[q5 * 64 + ((w * 2 + hi) ^ (q5 & 7)) * 8];
                sa = __builtin_amdgcn_mfma_f32_32x32x16_bf16(kf, qf[w], sa, 0, 0, 0);
            }
            if (act1) {
#pragma unroll
                for (int w = 0; w < 4; ++w) {
                    int key = 32 + q5;
                    bf16x8 kf = *(const bf16x8*)&K_lds[key * 64 + ((w * 2 + hi) ^ (key & 7)) * 8];
                    sb = __builtin_amdgcn_mfma_f32_32x32x16_bf16(kf, qf[w], sb, 0, 0, 0);
                }
            }
            __builtin_amdgcn_s_setprio(0);

            if (kt * 64 + 31 > wq0) {
#pragma unroll
                for (int r = 0; r < 16; ++r) {
                    int key = kt * 64 + (r & 3) + 8 * (r >> 2) + 4 * hi;
                    sa[r] = (key <= qg) ? sa[r] : -1e30f;
                }
            }
            if (act1 && (kt * 64 + 63 > wq0)) {
#pragma unroll
                for (int r = 0; r < 16; ++r) {
                    int key = kt * 64 + 32 + (r & 3) + 8 * (r >> 2) + 4 * hi;
                    sb[r] = (key <= qg) ? sb[r] : -1e30f;
                }
            }

            float rs = 0.f;
#pragma unroll
            for (int r = 0; r < 16; ++r) { sa[r] = hexp2(sa[r]); rs += sa[r]; }
            if (act1) {
#pragma unroll
                for (int r = 0; r < 16; ++r) { sb[r] = hexp2(sb[r]); rs += sb[r]; }
            }
            lsum += rs;

            __builtin_amdgcn_s_setprio(1);
#pragma unroll
            for (int st = 0; st < 2; ++st) {
                if (st == 1 && !act1) break;
                const f32x16& s = (st == 0) ? sa : sb;
                unsigned pkv[8];
#pragma unroll
                for (int i = 0; i < 8; ++i) pkv[i] = cvtpk(s[2 * i], s[2 * i + 1]);
#pragma unroll
                for (int ks = 0; ks < 2; ++ks) {
                    // permlane32_swap(a,b): a' = [a.lo, b.lo], b' = [a.hi, b.hi]
                    unsigned a0 = pkv[4 * ks],     b0 = pkv[4 * ks + 2];
                    unsigned a1 = pkv[4 * ks + 1], b1 = pkv[4 * ks + 3];
                    asm("v_permlane32_swap_b32 %0, %1" : "+v"(a0), "+v"(b0));
                    asm("v_permlane32_swap_b32 %0, %1" : "+v"(a1), "+v"(b1));
                    union { unsigned u[4]; bf16x8 v; } fr;
                    fr.u[0] = a0;
                    fr.u[1] = a1;
                    fr.u[2] = b0;
                    fr.u[3] = b1;
                    o0 = __builtin_amdgcn_mfma_f32_32x32x16_bf16(vfr[(st * 2 + ks) * 2],     fr.v, o0, 0, 0, 0);
                    o1 = __builtin_amdgcn_mfma_f32_32x32x16_bf16(vfr[(st * 2 + ks) * 2 + 1], fr.v, o1, 0, 0, 0);
                }
            }
            __builtin_amdgcn_s_setprio(0);
        }
    }
#undef KSTAGE2

    lsum += __shfl_xor(lsum, 32, 64);
    const float inv = 1.f / lsum;
    float* orow = out + ((long)b * T_ + qg) * E_ + h * HS_;
#pragma unroll
    for (int rg = 0; rg < 4; ++rg) {
        float4 v0, v1;
        v0.x = o0[rg * 4 + 0] * inv; v0.y = o0[rg * 4 + 1] * inv;
        v0.z = o0[rg * 4 + 2] * inv; v0.w = o0[rg * 4 + 3] * inv;
        v1.x = o1[rg * 4 + 0] * inv; v1.y = o1[rg * 4 + 1] * inv;
        v1.z = o1[rg * 4 + 2] * inv; v1.w = o1[rg * 4 + 3] * inv;
        *(float4*)&orow[8 * rg + 4 * hi]      = v0;
        *(float4*)&orow[32 + 8 * rg + 4 * hi] = v1;
    }
}

extern "C" void kernel_launch(void* const* d_in, const int* in_sizes, int n_in,
                              void* d_out, int out_size, void* d_ws, size_t ws_size,
                              hipStream_t stream) {
    const float* x     = (const float*)d_in[0];   // [4,2048,1024]
    const float* W_qkv = (const float*)d_in[1];   // [3072,1024]
    const float* b_qkv = (const float*)d_in[2];   // [3072]
    float* out = (float*)d_out;                   // [4,2048,1024]

    const long per = (long)64 * T_ * 64;          // 8,388,608 elems per buffer
    __hip_bfloat16* Qb = (__hip_bfloat16*)d_ws;
    __hip_bfloat16* Kb = Qb + per;
    __hip_bfloat16* Vf = Kb + per;                // fragment-major V
    short* Xb = (short*)(Vf + per);
    short* Wb = Xb + (long)M_ * E_;

    const long ncvt = ((long)M_ * E_ + (long)F_ * E_) / 8;
    cvt_bf16<<<(int)(ncvt / 256), 256, 0, stream>>>(x, W_qkv, Xb, Wb);

    qkv_gemm_mfma<<<768, 256, 0, stream>>>(Xb, Wb, b_qkv, Qb, Kb, Vf);

    attn_mfma10<<<1024, 256, 0, stream>>>(Qb, Kb, Vf, out);
}